// Round 10
// baseline (70.893 us; speedup 1.0000x reference)
//
#include <hip/hip_runtime.h>
#include <hip/hip_bf16.h>

// Problem constants (from reference)
#define KK 2
#define BB 4
#define VV 2000
#define DD 64
#define HH 4
#define DHH 64
#define PP 128
#define ALPHA_ 0.2f

// geometry
#define RPB 32                 // attention rows per tile (2 MFMA row-tiles)
#define YB  8                  // y-blocks per (kb,h)
#define NWV 4                  // waves per block
#define N_CAP 384              // max present rows per slice (mu=200, +13.7 sigma)
#define LSTR 66                // ushort stride per EWb row = 132 B (bank-safe)

typedef __attribute__((ext_vector_type(8))) short bf16x8;
typedef __attribute__((ext_vector_type(4))) float f32x4;

__device__ __forceinline__ float lrelu(float z) { return fmaxf(z, ALPHA_ * z); }
__device__ __forceinline__ float elu_(float z)  { return z > 0.f ? z : expm1f(z); }
__device__ __forceinline__ short f2bf(float f) {
  __hip_bfloat16 h = __float2bfloat16(f);
  return *reinterpret_cast<short*>(&h);
}
__device__ __forceinline__ float agent_acq_load(const float* p) {
  return __hip_atomic_load(p, __ATOMIC_ACQUIRE, __HIP_MEMORY_SCOPE_AGENT);
}

// ---------------------------------------------------------------------------
// Workspace (float offsets): LAT [K][B][256] @ 0 (2048); CTR (int)[36*16]
// @ 2048 (576). Both zeroed per call by one hipMemsetAsync (10496 B) —
// poison-safe and validation-safe. No other global intermediates exist.
// ---------------------------------------------------------------------------
#define OFF_LAT 0
#define OFF_CTR 2048

// ---- single compute kernel: per-block {compact, EW->LDS, stats, MFMA PV},
// tree-arrival fused finale. Block = (kb, y, h); 1 block/CU.
__global__ __launch_bounds__(256, 1) void k_fused(
    const float* __restrict__ E, const float* __restrict__ W,
    const float* __restrict__ a1, const float* __restrict__ a2,
    const float* __restrict__ x, const float* __restrict__ cls_w,
    const float* __restrict__ ac1, const float* __restrict__ ac2,
    const float* __restrict__ dW, const float* __restrict__ db,
    float* __restrict__ out, float* __restrict__ lat, int* __restrict__ ctr) {
  __shared__ unsigned short EWb[N_CAP][LSTR];  // 50688 B: gathered EW, bf16
  __shared__ int   Sl[N_CAP];                  // compacted indices
  __shared__ float G1l[N_CAP], G2l[N_CAP];     // gathered F1 / F2 (f32)
  __shared__ float SF1[RPB], SM[RPB], SIV[RPB];
  __shared__ float pooled[256], finp[2][PP], red[4][4];
  __shared__ int s_n, s_fin;

  const int kb = blockIdx.x;     // 0..7
  const int y  = blockIdx.y;     // 0..7
  const int h  = blockIdx.z;     // 0..3
  const int tid = threadIdx.x;
  const int wave = tid >> 6, lane = tid & 63;

  // ---- phase 0: in-block compaction of kb's present set (wave 0) ----
  if (wave == 0) {
    const float* xr = x + kb * VV;
    int base = 0;
    for (int t = 0; t * 64 < VV; ++t) {
      const int v = t * 64 + lane;
      const bool f = (v < VV) && (xr[v] > 0.f);
      const unsigned long long mm = __ballot(f);
      if (f) {
        const int pos = base + __popcll(mm & ((1ull << lane) - 1ull));
        if (pos < N_CAP) Sl[pos] = v;
      }
      base += __popcll(mm);
    }
    if (lane == 0) s_n = (base < N_CAP) ? base : N_CAP;
  }
  __syncthreads();
  const int n = s_n;
  const int nup = (n + 31) & ~31;

  // ---- phase 1: EW slice -> LDS (bf16), F1/F2 -> G1l/G2l (f32 math) ----
  {
    const float a1v = a1[h * DHH + lane];
    const float a2v = a2[h * DHH + lane];
    float wcol[DD];                       // W_h column for this lane
#pragma unroll
    for (int d = 0; d < DD; ++d) wcol[d] = W[(h * DD + d) * DHH + lane];
#pragma unroll 2
    for (int r = wave; r < nup; r += NWV) {
      if (r < n) {
        const int vu = __builtin_amdgcn_readfirstlane(Sl[r]);
        const float* Ev = E + vu * DD;    // wave-uniform base -> scalar loads
        float c0 = 0.f, c1 = 0.f, c2 = 0.f, c3 = 0.f;
#pragma unroll
        for (int d = 0; d < DD; d += 4) {
          c0 = fmaf(Ev[d + 0], wcol[d + 0], c0);
          c1 = fmaf(Ev[d + 1], wcol[d + 1], c1);
          c2 = fmaf(Ev[d + 2], wcol[d + 2], c2);
          c3 = fmaf(Ev[d + 3], wcol[d + 3], c3);
        }
        const float acc = (c0 + c1) + (c2 + c3);
        EWb[r][lane] = (unsigned short)f2bf(acc);
        float r1 = acc * a1v, r2 = acc * a2v;
#pragma unroll
        for (int s = 32; s; s >>= 1) { r1 += __shfl_xor(r1, s); r2 += __shfl_xor(r2, s); }
        if (lane == 0) { G1l[r] = r1; G2l[r] = r2; }
      } else {                            // zero-pad K-tail rows
        EWb[r][lane] = 0;
        if (lane == 0) { G1l[r] = 0.f; G2l[r] = 0.f; }
      }
    }
  }
  __syncthreads();

  // ---- phase 2: attention tiles (stats f32 + MFMA PV, B from LDS) ----
  const int nt = (n + RPB - 1) / RPB;
  if (y < nt) {
    const int col = (wave << 4) | (lane & 15);   // output/B column
    const int q   = lane >> 4;                   // K-quarter
    for (int tile = y; tile < nt; tile += YB) {
      const int r0w = tile * RPB + wave * 8;
      bool act[8]; float f1r[8];
#pragma unroll
      for (int i = 0; i < 8; ++i) {
        const int r = r0w + i;
        act[i] = r < n;
        f1r[i] = G1l[act[i] ? r : 0];
      }
      float m[8];
#pragma unroll
      for (int i = 0; i < 8; ++i) m[i] = -3.4e38f;
      for (int jb = lane; jb < n; jb += 64) {
        const float g = G2l[jb];
#pragma unroll
        for (int i = 0; i < 8; ++i) m[i] = fmaxf(m[i], lrelu(f1r[i] + g));
      }
#pragma unroll
      for (int s = 32; s; s >>= 1)
#pragma unroll
        for (int i = 0; i < 8; ++i) m[i] = fmaxf(m[i], __shfl_xor(m[i], s));
      float sm[8];
#pragma unroll
      for (int i = 0; i < 8; ++i) sm[i] = 0.f;
      for (int jb = lane; jb < n; jb += 64) {
        const float g = G2l[jb];
#pragma unroll
        for (int i = 0; i < 8; ++i) sm[i] += __expf(lrelu(f1r[i] + g) - m[i]);
      }
#pragma unroll
      for (int s = 32; s; s >>= 1)
#pragma unroll
        for (int i = 0; i < 8; ++i) sm[i] += __shfl_xor(sm[i], s);

      __syncthreads();  // previous tile's PV done reading stats
      if (lane == 0) {
#pragma unroll
        for (int i = 0; i < 8; ++i) {
          SF1[wave * 8 + i] = f1r[i];
          SM[wave * 8 + i]  = m[i];
          SIV[wave * 8 + i] = act[i] ? (1.f / sm[i]) : 0.f;
        }
      }
      __syncthreads();  // stats visible to all waves

      const int rl = lane & 15;
      const float f1a = SF1[rl],      ma = SM[rl],      ia = SIV[rl];
      const float f1b = SF1[16 + rl], mb = SM[16 + rl], ib = SIV[16 + rl];
      f32x4 acc0 = {0.f, 0.f, 0.f, 0.f}, acc1 = {0.f, 0.f, 0.f, 0.f};
      for (int kc = 0; kc < nup; kc += 32) {
        const int kq = kc + q * 8;
        const float4 ga = *reinterpret_cast<const float4*>(&G2l[kq]);
        const float4 gb = *reinterpret_cast<const float4*>(&G2l[kq + 4]);
        const float g[8] = {ga.x, ga.y, ga.z, ga.w, gb.x, gb.y, gb.z, gb.w};
        bf16x8 Bf;
#pragma unroll
        for (int t = 0; t < 8; ++t) Bf[t] = (short)EWb[kq + t][col];  // LDS, 2-way
        float pa[8], pb[8];
#pragma unroll
        for (int t = 0; t < 8; ++t) {
          const float gt = g[t];
          pa[t] = __expf(lrelu(f1a + gt) - ma) * ia;
          pb[t] = __expf(lrelu(f1b + gt) - mb) * ib;
        }
        if (kc + 32 > n) {  // K-tail: zero out-of-range columns
#pragma unroll
          for (int t = 0; t < 8; ++t)
            if (kq + t >= n) { pa[t] = 0.f; pb[t] = 0.f; }
        }
        bf16x8 A0, A1;
#pragma unroll
        for (int t = 0; t < 8; ++t) { A0[t] = f2bf(pa[t]); A1[t] = f2bf(pb[t]); }
        acc0 = __builtin_amdgcn_mfma_f32_16x16x32_bf16(A0, Bf, acc0, 0, 0, 0);
        acc1 = __builtin_amdgcn_mfma_f32_16x16x32_bf16(A1, Bf, acc1, 0, 0, 0);
      }
      // epilogue: lat[col] = max(0, max_rows elu(out)) — positives only
      float vmax = -3.4e38f;
#pragma unroll
      for (int r = 0; r < 4; ++r) {
        const int row0 = tile * RPB + (q << 2) + r;
        const int row1 = row0 + 16;
        if (row0 < n) vmax = fmaxf(vmax, acc0[r]);
        if (row1 < n) vmax = fmaxf(vmax, acc1[r]);
      }
      if (vmax > 0.f) {
        const int old = atomicMax(
            reinterpret_cast<int*>(&lat[kb * 256 + h * DHH + col]),
            __float_as_int(vmax));
        asm volatile("" : : "v"(old));  // RMW complete before arrival
      }
    }
  }

  // ---- tree arrival: leaf (kb,h) -> batch (kb&3); relaxed, no spinning ----
  __syncthreads();   // drains all VMEM (incl. lat atomics) of every wave
  if (tid == 0) {
    int fin_ = 0;
    const int l = atomicAdd(&ctr[(kb * HH + h) * 16], 1);      // relaxed RMW
    if (l == YB - 1) {
      const int r = atomicAdd(&ctr[(32 + (kb & 3)) * 16], 1);  // relaxed RMW
      fin_ = (r == KK * HH - 1);
    }
    s_fin = fin_;
  }
  __syncthreads();
  if (!s_fin) return;

  // ---- finale for batch b = kb&3 (one block; acquire loads on lat) ----
  const int b = kb & 3;
  const float cw = cls_w[tid];
  const float l0 = fmaxf(agent_acq_load(&lat[(0 * BB + b) * 256 + tid]), 0.f);
  const float l1 = fmaxf(agent_acq_load(&lat[(1 * BB + b) * 256 + tid]), 0.f);
  float t0 = cw * ac1[tid];
  float t1 = cw * ac2[tid];
  float t2 = l0 * ac2[tid];
  float t3 = l1 * ac2[tid];
#pragma unroll
  for (int s = 32; s; s >>= 1) {
    t0 += __shfl_xor(t0, s); t1 += __shfl_xor(t1, s);
    t2 += __shfl_xor(t2, s); t3 += __shfl_xor(t3, s);
  }
  if (lane == 0) { red[wave][0] = t0; red[wave][1] = t1; red[wave][2] = t2; red[wave][3] = t3; }
  __syncthreads();
  const float ca1 = red[0][0] + red[1][0] + red[2][0] + red[3][0];
  const float d0  = red[0][1] + red[1][1] + red[2][1] + red[3][1];
  const float d1  = red[0][2] + red[1][2] + red[2][2] + red[3][2];
  const float d2  = red[0][3] + red[1][3] + red[2][3] + red[3][3];
  const float e0 = lrelu(ca1 + d0), e1 = lrelu(ca1 + d1), e2 = lrelu(ca1 + d2);
  const float mm = fmaxf(e0, fmaxf(e1, e2));
  const float x0 = __expf(e0 - mm), x1 = __expf(e1 - mm), x2 = __expf(e2 - mm);
  const float invs = 1.f / (x0 + x1 + x2);
  pooled[tid] = (x0 * cw + x1 * l0 + x2 * l1) * invs;
  __syncthreads();
  {  // dense head: f-dim split 2-way, 8 accumulators (~32 loads in flight)
    const int o = tid & (PP - 1), half = tid >> 7;
    const float* dWc = dW + (half * 128) * PP + o;
    const float* pl = &pooled[half * 128];
    float a0 = 0.f, b1 = 0.f, b2 = 0.f, b3 = 0.f;
    float a4 = 0.f, a5 = 0.f, a6 = 0.f, a7 = 0.f;
#pragma unroll
    for (int f = 0; f < 128; f += 8) {
      a0 = fmaf(pl[f + 0], dWc[(f + 0) * PP], a0);
      b1 = fmaf(pl[f + 1], dWc[(f + 1) * PP], b1);
      b2 = fmaf(pl[f + 2], dWc[(f + 2) * PP], b2);
      b3 = fmaf(pl[f + 3], dWc[(f + 3) * PP], b3);
      a4 = fmaf(pl[f + 4], dWc[(f + 4) * PP], a4);
      a5 = fmaf(pl[f + 5], dWc[(f + 5) * PP], a5);
      a6 = fmaf(pl[f + 6], dWc[(f + 6) * PP], a6);
      a7 = fmaf(pl[f + 7], dWc[(f + 7) * PP], a7);
    }
    finp[half][o] = ((a0 + b1) + (b2 + b3)) + ((a4 + a5) + (a6 + a7));
  }
  __syncthreads();
  if (tid < PP) out[b * PP + tid] = elu_(db[tid] + finp[0][tid] + finp[1][tid]);
}

extern "C" void kernel_launch(void* const* d_in, const int* in_sizes, int n_in,
                              void* d_out, int out_size, void* d_ws, size_t ws_size,
                              hipStream_t stream) {
  const float* x     = (const float*)d_in[0];
  const float* E     = (const float*)d_in[1];
  const float* W     = (const float*)d_in[2];
  const float* a1    = (const float*)d_in[3];
  const float* a2    = (const float*)d_in[4];
  const float* cls_w = (const float*)d_in[5];
  const float* ac1   = (const float*)d_in[6];
  const float* ac2   = (const float*)d_in[7];
  const float* dW    = (const float*)d_in[8];
  const float* db    = (const float*)d_in[9];
  float* out = (float*)d_out;

  float* ws  = (float*)d_ws;
  float* LAT = ws + OFF_LAT;
  int*   CTR = (int*)(ws + OFF_CTR);

  // zero LAT (2048 f) + CTR (576 i) in one tiny memset node
  hipMemsetAsync(LAT, 0, (2048 + 576) * sizeof(float), stream);
  k_fused<<<dim3(KK * BB, YB, HH), 256, 0, stream>>>(
      E, W, a1, a2, x, cls_w, ac1, ac2, dW, db, out, LAT, CTR);
}

// Round 11
// 32.727 us; speedup vs baseline: 2.1662x; 2.1662x over previous
//
#include <hip/hip_runtime.h>
#include <hip/hip_bf16.h>

// Problem constants (from reference)
#define KK 2
#define BB 4
#define VV 2000
#define DD 64
#define HH 4
#define DHH 64
#define PP 128
#define ALPHA_ 0.2f

// k_attn geometry
#define RPB 32                // rows per block-tile (2 MFMA row-tiles)
#define YB  8                 // y-blocks (tiles strided by YB)
#define NFIN 4                // dedicated finale blocks (bid 0..3)

typedef __attribute__((ext_vector_type(8))) short bf16x8;
typedef __attribute__((ext_vector_type(4))) float f32x4;

__device__ __forceinline__ float lrelu(float z) { return fmaxf(z, ALPHA_ * z); }
__device__ __forceinline__ float elu_(float z)  { return z > 0.f ? z : expm1f(z); }
__device__ __forceinline__ short f2bf(float f) {
  __hip_bfloat16 h = __float2bfloat16(f);
  return *reinterpret_cast<short*>(&h);
}
__device__ __forceinline__ float agent_acq_load(const float* p) {
  return __hip_atomic_load(p, __ATOMIC_ACQUIRE, __HIP_MEMORY_SCOPE_AGENT);
}
__device__ __forceinline__ int agent_acq_load_i(const int* p) {
  return __hip_atomic_load(p, __ATOMIC_ACQUIRE, __HIP_MEMORY_SCOPE_AGENT);
}

// ---------------------------------------------------------------------------
// Workspace layout (float offsets):
//   EW  [H][V][DH]   : 0        (512000)
//   F1  [H][V]       : 512000   (8000)
//   F2  [H][V]       : 520000   (8000)
//   LAT [K][B][256]  : 528000   (2048)
//   CNT (int)[8]     : 530048   (8)
//   S   (int)[K*B][V]: 530056   (16000)
//   CTR (int)[36*16] : 546056   — 32 leaf lines + 4 batch lines, 64 B apart;
//                                zeroed by k_pre each call (plain stores)
// ---------------------------------------------------------------------------
#define OFF_EW   0
#define OFF_F1   512000
#define OFF_F2   520000
#define OFF_LAT  528000
#define OFF_CNT  530048
#define OFF_S    530056
#define OFF_CTR  546056

// ---- kernel 0 (fused): EW/F1/F2 precompute (present rows only) + compaction
__global__ __launch_bounds__(256) void k_pre(
    const float* __restrict__ E, const float* __restrict__ W,
    const float* __restrict__ a1, const float* __restrict__ a2,
    const float* __restrict__ x,
    float* __restrict__ EW, float* __restrict__ F1, float* __restrict__ F2,
    int* __restrict__ S, int* __restrict__ cnt, float* __restrict__ lat,
    int* __restrict__ ctr) {
  const int bid = blockIdx.x;
  const int wave = threadIdx.x >> 6, lane = threadIdx.x & 63;
  if (bid < 2000) {
    const int h = bid / 500;                 // h-major: W_h stays L1-hot
    const int v = (bid % 500) * 4 + wave;
    bool pres = false;                       // skip rows absent in all slices
#pragma unroll
    for (int kb = 0; kb < KK * BB; ++kb) pres |= (x[kb * VV + v] > 0.f);
    if (!pres) return;
    const float* Wh = W + h * DD * DHH;
    const float* Ev = E + v * DD;
    float acc = 0.f;
#pragma unroll 8
    for (int d = 0; d < DD; ++d) acc = fmaf(Ev[d], Wh[d * DHH + lane], acc);
    EW[(size_t)(h * VV + v) * DHH + lane] = acc;
    float r1 = acc * a1[h * DHH + lane];
    float r2 = acc * a2[h * DHH + lane];
#pragma unroll
    for (int s = 32; s; s >>= 1) { r1 += __shfl_xor(r1, s); r2 += __shfl_xor(r2, s); }
    if (lane == 0) { F1[h * VV + v] = r1; F2[h * VV + v] = r2; }
  } else {
    if (wave != 0) return;
    const int kb = bid - 2000;  // 0..7
    if (kb == 0)                // zero arrival-counter tree (plain stores;
      for (int i = lane; i < 36 * 16; i += 64) ctr[i] = 0;  // flushed at EOK)
    for (int i = lane; i < 256; i += 64) lat[kb * 256 + i] = 0.f;
    const float* xr = x + kb * VV;
    int base = 0;
    for (int t = 0; t * 64 < VV; ++t) {
      const int v = t * 64 + lane;
      const bool f = (v < VV) && (xr[v] > 0.f);
      const unsigned long long m = __ballot(f);
      if (f) S[kb * VV + base + __popcll(m & ((1ull << lane) - 1ull))] = v;
      base += __popcll(m);
    }
    if (lane == 0) cnt[kb] = base;
  }
}

// ---- kernel 1: attention via MFMA + dedicated prefetch/spin finale --------
// Flat grid of 4+256 blocks. bid 0..3: finale block for batch b=bid —
// prefetches dW into 128 VGPRs/thread (forced early), spins on its batch
// counter (1 lane, s_sleep), then runs the pooling+dense head from regs.
// bid 4..259: attention block (kb,y,h) — identical math to R9; arrival tree
// with relaxed RMWs whose returns are consumed (completion-chained).
__global__ __launch_bounds__(256) void k_attn(
    const float* __restrict__ EW, const float* __restrict__ F1,
    const float* __restrict__ F2, const int* __restrict__ S,
    const int* __restrict__ cnt, float* __restrict__ lat,
    const float* __restrict__ cls_w, const float* __restrict__ ac1,
    const float* __restrict__ ac2, const float* __restrict__ dW,
    const float* __restrict__ db, float* __restrict__ out,
    int* __restrict__ ctr) {
  __shared__ int   Sl[2048];     // compacted indices (padded)
  __shared__ float G2l[2048];    // gathered F2 (padded with 0)
  __shared__ float SF1[RPB], SM[RPB], SIV[RPB];
  __shared__ float pooled[256];
  __shared__ float finp[2][PP];
  __shared__ float red[4][4];

  const int bid = blockIdx.x;
  const int tid = threadIdx.x;
  const int wave = tid >> 6, lane = tid & 63;

  if (bid < NFIN) {
    // ================= finale block for batch b =================
    const int b = bid;
    const int o = tid & (PP - 1), half = tid >> 7;
    // prefetch dW slice into registers (issued before the spin)
    float dwr[128];
    const float* dWc = dW + (half * 128) * PP + o;
#pragma unroll
    for (int f = 0; f < 128; ++f) dwr[f] = dWc[f * PP];
    const float cw = cls_w[tid];
    const float v1 = ac1[tid], v2 = ac2[tid];
    const float dbv = (tid < PP) ? db[tid] : 0.f;
    {  // force all prefetch loads to issue before the spin loop
      float chk = 0.f;
#pragma unroll
      for (int f = 0; f < 128; ++f) chk += dwr[f];
      asm volatile("" : : "v"(chk), "v"(cw), "v"(v1), "v"(v2), "v"(dbv));
    }
    // spin until all 8 (kb,h) groups of this batch have arrived
    if (tid == 0) {
      while (agent_acq_load_i(&ctr[(32 + b) * 16]) < KK * HH)
        __builtin_amdgcn_s_sleep(8);
    }
    __syncthreads();
    // pooling (acquire loads on lat)
    const float l0 = agent_acq_load(&lat[(0 * BB + b) * 256 + tid]);
    const float l1 = agent_acq_load(&lat[(1 * BB + b) * 256 + tid]);
    float t0 = cw * v1, t1 = cw * v2, t2 = l0 * v2, t3 = l1 * v2;
#pragma unroll
    for (int s = 32; s; s >>= 1) {
      t0 += __shfl_xor(t0, s); t1 += __shfl_xor(t1, s);
      t2 += __shfl_xor(t2, s); t3 += __shfl_xor(t3, s);
    }
    if (lane == 0) { red[wave][0] = t0; red[wave][1] = t1; red[wave][2] = t2; red[wave][3] = t3; }
    __syncthreads();
    const float ca1 = red[0][0] + red[1][0] + red[2][0] + red[3][0];
    const float d0  = red[0][1] + red[1][1] + red[2][1] + red[3][1];
    const float d1  = red[0][2] + red[1][2] + red[2][2] + red[3][2];
    const float d2  = red[0][3] + red[1][3] + red[2][3] + red[3][3];
    const float e0 = lrelu(ca1 + d0), e1 = lrelu(ca1 + d1), e2 = lrelu(ca1 + d2);
    const float mm = fmaxf(e0, fmaxf(e1, e2));
    const float x0 = __expf(e0 - mm), x1 = __expf(e1 - mm), x2 = __expf(e2 - mm);
    const float invs = 1.f / (x0 + x1 + x2);
    pooled[tid] = (x0 * cw + x1 * l0 + x2 * l1) * invs;
    __syncthreads();
    // dense head from registers: 8 accumulators over LDS-broadcast pooled
    {
      const float* pl = &pooled[half * 128];
      float a0 = 0.f, b1 = 0.f, b2 = 0.f, b3 = 0.f;
      float a4 = 0.f, a5 = 0.f, a6 = 0.f, a7 = 0.f;
#pragma unroll
      for (int f = 0; f < 128; f += 8) {
        a0 = fmaf(pl[f + 0], dwr[f + 0], a0);
        b1 = fmaf(pl[f + 1], dwr[f + 1], b1);
        b2 = fmaf(pl[f + 2], dwr[f + 2], b2);
        b3 = fmaf(pl[f + 3], dwr[f + 3], b3);
        a4 = fmaf(pl[f + 4], dwr[f + 4], a4);
        a5 = fmaf(pl[f + 5], dwr[f + 5], a5);
        a6 = fmaf(pl[f + 6], dwr[f + 6], a6);
        a7 = fmaf(pl[f + 7], dwr[f + 7], a7);
      }
      finp[half][o] = ((a0 + b1) + (b2 + b3)) + ((a4 + a5) + (a6 + a7));
    }
    __syncthreads();
    if (tid < PP) out[b * PP + tid] = elu_(dbv + finp[0][tid] + finp[1][tid]);
    return;
  }

  // ================= attention block (kb, y, h) =================
  const int idx = bid - NFIN;
  const int kb = idx & 7;
  const int y  = (idx >> 3) & 7;
  const int h  = idx >> 6;
  const int n = cnt[kb];
  const int nt = (n + RPB - 1) / RPB;

  if (y < nt) {
    const int nup = (n + 31) & ~31;
    const int* Skb = S + kb * VV;
    const float* F2h = F2 + h * VV;
    const float* F1h = F1 + h * VV;
    const float* EWh = EW + (size_t)h * VV * DHH;

    // stage indices + gathered F2 once per block
    for (int j = tid; j < nup; j += 256) {
      const int v = (j < n) ? Skb[j] : Skb[0];
      Sl[j] = v;
      G2l[j] = (j < n) ? F2h[v] : 0.f;
    }
    __syncthreads();

    const int col = (wave << 4) | (lane & 15);   // output/B column
    const int q   = lane >> 4;                   // K-quarter
    const float* EWcol = EWh + col;

    for (int tile = y; tile < nt; tile += YB) {
      // ---- softmax stats: wave owns rows r0w..r0w+8 ----
      const int r0w = tile * RPB + wave * 8;
      bool act[8]; float f1r[8];
#pragma unroll
      for (int i = 0; i < 8; ++i) {
        const int r = r0w + i;
        act[i] = r < n;
        f1r[i] = F1h[Sl[act[i] ? r : 0]];   // wave-uniform gather
      }
      float m[8];
#pragma unroll
      for (int i = 0; i < 8; ++i) m[i] = -3.4e38f;
      for (int jb = lane; jb < n; jb += 64) {
        const float g = G2l[jb];
#pragma unroll
        for (int i = 0; i < 8; ++i) m[i] = fmaxf(m[i], lrelu(f1r[i] + g));
      }
#pragma unroll
      for (int s = 32; s; s >>= 1)
#pragma unroll
        for (int i = 0; i < 8; ++i) m[i] = fmaxf(m[i], __shfl_xor(m[i], s));
      float sm[8];
#pragma unroll
      for (int i = 0; i < 8; ++i) sm[i] = 0.f;
      for (int jb = lane; jb < n; jb += 64) {
        const float g = G2l[jb];
#pragma unroll
        for (int i = 0; i < 8; ++i) sm[i] += __expf(lrelu(f1r[i] + g) - m[i]);
      }
#pragma unroll
      for (int s = 32; s; s >>= 1)
#pragma unroll
        for (int i = 0; i < 8; ++i) sm[i] += __shfl_xor(sm[i], s);

      __syncthreads();  // previous tile's MFMA phase done reading stats
      if (lane == 0) {
#pragma unroll
        for (int i = 0; i < 8; ++i) {
          SF1[wave * 8 + i] = f1r[i];
          SM[wave * 8 + i]  = m[i];
          SIV[wave * 8 + i] = act[i] ? (1.f / sm[i]) : 0.f;
        }
      }
      __syncthreads();  // stats visible to all waves

      // ---- MFMA PV: wave w computes cols 16w..16w+16, rows 0..31 ----
      const int rl = lane & 15;
      const float f1a = SF1[rl],      ma = SM[rl],      ia = SIV[rl];
      const float f1b = SF1[16 + rl], mb = SM[16 + rl], ib = SIV[16 + rl];
      f32x4 acc0 = {0.f, 0.f, 0.f, 0.f}, acc1 = {0.f, 0.f, 0.f, 0.f};
      for (int kc = 0; kc < nup; kc += 32) {
        const int kq = kc + q * 8;
        const int4 va = *reinterpret_cast<const int4*>(&Sl[kq]);
        const int4 vb = *reinterpret_cast<const int4*>(&Sl[kq + 4]);
        const float4 ga = *reinterpret_cast<const float4*>(&G2l[kq]);
        const float4 gb = *reinterpret_cast<const float4*>(&G2l[kq + 4]);
        float bv[8];
        bv[0] = EWcol[(size_t)va.x * DHH];
        bv[1] = EWcol[(size_t)va.y * DHH];
        bv[2] = EWcol[(size_t)va.z * DHH];
        bv[3] = EWcol[(size_t)va.w * DHH];
        bv[4] = EWcol[(size_t)vb.x * DHH];
        bv[5] = EWcol[(size_t)vb.y * DHH];
        bv[6] = EWcol[(size_t)vb.z * DHH];
        bv[7] = EWcol[(size_t)vb.w * DHH];
        const float g[8] = {ga.x, ga.y, ga.z, ga.w, gb.x, gb.y, gb.z, gb.w};
        float pa[8], pb[8];
#pragma unroll
        for (int t = 0; t < 8; ++t) {
          const float gt = g[t];
          pa[t] = __expf(lrelu(f1a + gt) - ma) * ia;
          pb[t] = __expf(lrelu(f1b + gt) - mb) * ib;
        }
        if (kc + 32 > n) {  // K-tail: zero out-of-range columns
#pragma unroll
          for (int t = 0; t < 8; ++t)
            if (kq + t >= n) { pa[t] = 0.f; pb[t] = 0.f; }
        }
        bf16x8 A0, A1, Bf;
#pragma unroll
        for (int t = 0; t < 8; ++t) {
          A0[t] = f2bf(pa[t]);
          A1[t] = f2bf(pb[t]);
          Bf[t] = f2bf(bv[t]);
        }
        acc0 = __builtin_amdgcn_mfma_f32_16x16x32_bf16(A0, Bf, acc0, 0, 0, 0);
        acc1 = __builtin_amdgcn_mfma_f32_16x16x32_bf16(A1, Bf, acc1, 0, 0, 0);
      }
      // epilogue: lat[col] = max(0, max_rows elu(out)) — only positives matter
      float vmax = -3.4e38f;
#pragma unroll
      for (int r = 0; r < 4; ++r) {
        const int row0 = tile * RPB + (q << 2) + r;
        const int row1 = row0 + 16;
        if (row0 < n) vmax = fmaxf(vmax, acc0[r]);
        if (row1 < n) vmax = fmaxf(vmax, acc1[r]);
      }
      if (vmax > 0.f) {
        const int old = atomicMax(
            reinterpret_cast<int*>(&lat[kb * 256 + h * DHH + col]),
            __float_as_int(vmax));
        // consume result: the RMW is complete at the coherence point before
        // this wave can reach the arrival tree
        asm volatile("" : : "v"(old));
      }
    }
  }

  // ---- tree arrival: leaf (kb,h) -> batch (kb&3); relaxed, no spinning ----
  __syncthreads();   // drains all VMEM (incl. lat atomics) of every wave
  if (tid == 0) {
    const int l = atomicAdd(&ctr[(kb * HH + h) * 16], 1);      // relaxed RMW
    if (l == YB - 1) {  // last y-block of this (kb,h) group (l was waited on)
      const int r = atomicAdd(&ctr[(32 + (kb & 3)) * 16], 1);  // relaxed RMW
      asm volatile("" : : "v"(r));
    }
  }
}

extern "C" void kernel_launch(void* const* d_in, const int* in_sizes, int n_in,
                              void* d_out, int out_size, void* d_ws, size_t ws_size,
                              hipStream_t stream) {
  const float* x     = (const float*)d_in[0];
  const float* E     = (const float*)d_in[1];
  const float* W     = (const float*)d_in[2];
  const float* a1    = (const float*)d_in[3];
  const float* a2    = (const float*)d_in[4];
  const float* cls_w = (const float*)d_in[5];
  const float* ac1   = (const float*)d_in[6];
  const float* ac2   = (const float*)d_in[7];
  const float* dW    = (const float*)d_in[8];
  const float* db    = (const float*)d_in[9];
  float* out = (float*)d_out;

  float* ws  = (float*)d_ws;
  float* EW  = ws + OFF_EW;
  float* F1  = ws + OFF_F1;
  float* F2  = ws + OFF_F2;
  float* LAT = ws + OFF_LAT;
  int*   CNT = (int*)(ws + OFF_CNT);
  int*   S   = (int*)(ws + OFF_S);
  int*   CTR = (int*)(ws + OFF_CTR);

  k_pre<<<2008, 256, 0, stream>>>(E, W, a1, a2, x, EW, F1, F2, S, CNT, LAT, CTR);
  k_attn<<<NFIN + KK * BB * YB * HH, 256, 0, stream>>>(
      EW, F1, F2, S, CNT, LAT, cls_w, ac1, ac2, dW, db, out, CTR);
}